// Round 5
// baseline (693.482 us; speedup 1.0000x reference)
//
#include <hip/hip_runtime.h>
#include <hip/hip_bf16.h>
#include <hip/hip_fp16.h>

#define NODES   50000
#define E_TRAIN 600000
#define E_SCORE 200000

typedef unsigned short ushort_t;
typedef __attribute__((ext_vector_type(8))) short bf16x8;
typedef __attribute__((ext_vector_type(4))) float f32x4;

static __device__ __forceinline__ float bf2f(unsigned short u) {
    return __uint_as_float((unsigned int)u << 16);
}
static __device__ __forceinline__ unsigned short f2bf(float f) {
    __hip_bfloat16 h = __float2bfloat16(f);
    return *reinterpret_cast<unsigned short*>(&h);
}
static __device__ __forceinline__ unsigned short f2h(float f) {
    __half h = __float2half(f);
    return *reinterpret_cast<unsigned short*>(&h);
}
static __device__ __forceinline__ float2 u2f2(unsigned int u) {
    __half2 h = *reinterpret_cast<__half2*>(&u);
    return __half22float2(h);
}
static __device__ __forceinline__ unsigned int f22u(float a, float b) {
    __half2 h = __floats2half2_rn(a, b);
    return *reinterpret_cast<unsigned int*>(&h);
}
static __device__ __forceinline__ unsigned int f22u_bf(float a, float b) {
    return (unsigned int)f2bf(a) | ((unsigned int)f2bf(b) << 16);
}

// ============ K2: detect dtype (block 0) + degree count (all blocks) ============
__global__ __launch_bounds__(256) void deg_detect_kernel(
    const int* __restrict__ tcol, int* __restrict__ counts,
    const unsigned int* __restrict__ xw, int* __restrict__ flag, int E)
{
    if (blockIdx.x == 0) {
        __shared__ int cnt;
        if (threadIdx.x == 0) cnt = 0;
        __syncthreads();
        unsigned int w = xw[threadIdx.x];
        unsigned short lo = (unsigned short)(w & 0xFFFFu);
        int e = (lo >> 7) & 0xFF;
        if (e >= 100 && e <= 140) atomicAdd(&cnt, 1);
        __syncthreads();
        if (threadIdx.x == 0) flag[0] = (cnt >= 150) ? 1 : 0;
    }
    for (int e = blockIdx.x * 256 + threadIdx.x; e < E; e += gridDim.x * 256)
        atomicAdd(&counts[tcol[e]], 1);
}

// ============ K3: block 0 = scan + dinv; blocks 1..4 = weight convert ============
__global__ __launch_bounds__(1024) void scan_convert_kernel(
    const int* __restrict__ counts, int* __restrict__ row_start,
    int* __restrict__ cursor, float* __restrict__ dinv,
    const void* __restrict__ W1, const void* __restrict__ b1,
    const void* __restrict__ W2, const void* __restrict__ b2,
    ushort_t* __restrict__ W1T, float* __restrict__ W1f,
    ushort_t* __restrict__ W2T, float* __restrict__ W2f,
    float* __restrict__ b1f, float* __restrict__ b2f,
    const int* __restrict__ flag)
{
    if (blockIdx.x == 0) {
        __shared__ int ts[1024];
        const int t = threadIdx.x;
        const int CH = 49;                       // 1024*49 >= 50000
        int base = t * CH;
        int s = 0;
        for (int i = 0; i < CH; ++i) {
            int idx = base + i;
            if (idx < NODES) s += counts[idx];
        }
        ts[t] = s;
        __syncthreads();
        for (int off = 1; off < 1024; off <<= 1) {   // Hillis-Steele inclusive
            int v = (t >= off) ? ts[t - off] : 0;
            __syncthreads();
            ts[t] += v;
            __syncthreads();
        }
        int run = ts[t] - s;                     // exclusive prefix
        for (int i = 0; i < CH; ++i) {
            int idx = base + i;
            if (idx >= NODES) break;
            int c = counts[idx];
            row_start[idx] = run;
            cursor[idx]    = run;
            dinv[idx]      = rsqrtf((float)c + 1.0f);
            run += c;
        }
    } else {
        int tid = (blockIdx.x - 1) * 1024 + threadIdx.x;   // 0..4095
        bool isbf = flag[0] != 0;
        for (int j = tid; j < 128 * 128; j += 4096) {
            int k = j >> 7, n = j & 127;
            float f; unsigned short raw;
            if (isbf) { raw = ((const ushort_t*)W1)[j]; f = bf2f(raw); }
            else      { f = ((const float*)W1)[j];      raw = f2bf(f); }
            W1f[j] = f;
            W1T[n * 128 + k] = raw;
        }
        for (int j = tid; j < 128 * 64; j += 4096) {
            int k = j >> 6, n = j & 63;
            float f; unsigned short raw;
            if (isbf) { raw = ((const ushort_t*)W2)[j]; f = bf2f(raw); }
            else      { f = ((const float*)W2)[j];      raw = f2bf(f); }
            W2f[j] = f;
            W2T[n * 128 + k] = raw;
        }
        if (tid < 128) b1f[tid] = isbf ? bf2f(((const ushort_t*)b1)[tid]) : ((const float*)b1)[tid];
        if (tid < 64)  b2f[tid] = isbf ? bf2f(((const ushort_t*)b2)[tid]) : ((const float*)b2)[tid];
    }
}

// ============ K4: blocks [0,FILLB) = CSR fill; rest = GEMM1 (MFMA bf16 / scalar) ====
#define FILLB 128
__global__ __launch_bounds__(256) void fill_gemm1_kernel(
    const int* __restrict__ trow, const int* __restrict__ tcol,
    int* __restrict__ cursor, int* __restrict__ esrc,
    const void* __restrict__ x, const ushort_t* __restrict__ W1T,
    const float* __restrict__ W1f, const float* __restrict__ dinv,
    ushort_t* __restrict__ g1, const int* __restrict__ flag)
{
    if (blockIdx.x < FILLB) {
        for (int e = blockIdx.x * 256 + threadIdx.x; e < E_TRAIN; e += FILLB * 256) {
            int d = tcol[e];
            int p = atomicAdd(&cursor[d], 1);
            esrc[p] = trow[e];
        }
        return;
    }
    const int bb = blockIdx.x - FILLB;           // 0..781
    const bool isbf = flag[0] != 0;
    if (isbf) {
        const int lane = threadIdx.x & 63, wave = threadIdx.x >> 6;
        const int n = lane & 15, quad = lane >> 4;
        const int wr0 = bb * 64 + wave * 16;
        const ushort_t* xu = (const ushort_t*)x;
        int rowA = wr0 + n; if (rowA > NODES - 1) rowA = NODES - 1;
        f32x4 acc[8];
        #pragma unroll
        for (int ct = 0; ct < 8; ++ct) acc[ct] = (f32x4){0.f, 0.f, 0.f, 0.f};
        #pragma unroll
        for (int kc = 0; kc < 4; ++kc) {
            bf16x8 a = *(const bf16x8*)(xu + (long)rowA * 128 + kc * 32 + quad * 8);
            #pragma unroll
            for (int ct = 0; ct < 8; ++ct) {
                bf16x8 b = *(const bf16x8*)(W1T + (ct * 16 + n) * 128 + kc * 32 + quad * 8);
                acc[ct] = __builtin_amdgcn_mfma_f32_16x16x32_bf16(a, b, acc[ct], 0, 0, 0);
            }
        }
        float sc[4]; int orow[4];
        #pragma unroll
        for (int r = 0; r < 4; ++r) {
            orow[r] = wr0 + quad * 4 + r;
            sc[r] = (orow[r] < NODES) ? dinv[orow[r]] : 0.f;
        }
        #pragma unroll
        for (int ct = 0; ct < 8; ++ct)
            #pragma unroll
            for (int r = 0; r < 4; ++r)
                if (orow[r] < NODES)
                    g1[(long)orow[r] * 128 + ct * 16 + n] = f2h(acc[ct][r] * sc[r]);
    } else {
        const float* xf = (const float*)x;
        for (long idx = (long)bb * 256 + threadIdx.x; idx < (long)NODES * 128; idx += 782L * 256) {
            int row = (int)(idx >> 7), col = (int)(idx & 127);
            float acc = 0.f;
            for (int k = 0; k < 128; ++k) acc += xf[(long)row * 128 + k] * W1f[k * 128 + col];
            g1[idx] = f2h(acc * dinv[row]);
        }
    }
}

// ============ K5: gather layer 1 (wave/dest, fp16 256 B rows) -> h1 (bf16|fp32) ======
__global__ __launch_bounds__(256) void gather1_kernel(
    const unsigned int* __restrict__ g1, const int* __restrict__ row_start,
    const int* __restrict__ counts, const int* __restrict__ esrc,
    const float* __restrict__ dinv, const float* __restrict__ bias,
    void* __restrict__ h1, const int* __restrict__ flag)
{
    int d = blockIdx.x * 4 + (threadIdx.x >> 6);
    int l = threadIdx.x & 63;
    int start = row_start[d], cnt = counts[d];
    float2 acc = make_float2(0.f, 0.f);
    int j = 0;
    for (; j + 4 <= cnt; j += 4) {
        int s0 = esrc[start + j + 0], s1 = esrc[start + j + 1];
        int s2 = esrc[start + j + 2], s3 = esrc[start + j + 3];
        float2 f0 = u2f2(g1[(long)s0 * 64 + l]);
        float2 f1 = u2f2(g1[(long)s1 * 64 + l]);
        float2 f2 = u2f2(g1[(long)s2 * 64 + l]);
        float2 f3 = u2f2(g1[(long)s3 * 64 + l]);
        acc.x += (f0.x + f1.x) + (f2.x + f3.x);
        acc.y += (f0.y + f1.y) + (f2.y + f3.y);
    }
    for (; j < cnt; ++j) {
        float2 f = u2f2(g1[(long)esrc[start + j] * 64 + l]);
        acc.x += f.x; acc.y += f.y;
    }
    float2 gd = u2f2(g1[(long)d * 64 + l]);
    float di = dinv[d];
    float2 b = *(const float2*)&bias[2 * l];
    float v0 = fmaxf(di * (acc.x + gd.x) + b.x, 0.f);
    float v1 = fmaxf(di * (acc.y + gd.y) + b.y, 0.f);
    if (flag[0]) ((unsigned int*)h1)[(long)d * 64 + l] = f22u_bf(v0, v1);
    else         *(float2*)&((float*)h1)[(long)d * 128 + 2 * l] = make_float2(v0, v1);
}

// ============ K6: GEMM2 (MFMA bf16 / scalar fp32): g2 = dinv*(h1 @ W2), fp16 ========
__global__ __launch_bounds__(256) void gemm2_kernel(
    const void* __restrict__ h1, const ushort_t* __restrict__ W2T,
    const float* __restrict__ W2f, const float* __restrict__ dinv,
    ushort_t* __restrict__ g2, const int* __restrict__ flag)
{
    const bool isbf = flag[0] != 0;
    if (isbf) {
        const int lane = threadIdx.x & 63, wave = threadIdx.x >> 6;
        const int n = lane & 15, quad = lane >> 4;
        const int wr0 = blockIdx.x * 64 + wave * 16;
        const ushort_t* hu = (const ushort_t*)h1;
        int rowA = wr0 + n; if (rowA > NODES - 1) rowA = NODES - 1;
        f32x4 acc[4];
        #pragma unroll
        for (int ct = 0; ct < 4; ++ct) acc[ct] = (f32x4){0.f, 0.f, 0.f, 0.f};
        #pragma unroll
        for (int kc = 0; kc < 4; ++kc) {
            bf16x8 a = *(const bf16x8*)(hu + (long)rowA * 128 + kc * 32 + quad * 8);
            #pragma unroll
            for (int ct = 0; ct < 4; ++ct) {
                bf16x8 b = *(const bf16x8*)(W2T + (ct * 16 + n) * 128 + kc * 32 + quad * 8);
                acc[ct] = __builtin_amdgcn_mfma_f32_16x16x32_bf16(a, b, acc[ct], 0, 0, 0);
            }
        }
        float sc[4]; int orow[4];
        #pragma unroll
        for (int r = 0; r < 4; ++r) {
            orow[r] = wr0 + quad * 4 + r;
            sc[r] = (orow[r] < NODES) ? dinv[orow[r]] : 0.f;
        }
        #pragma unroll
        for (int ct = 0; ct < 4; ++ct)
            #pragma unroll
            for (int r = 0; r < 4; ++r)
                if (orow[r] < NODES)
                    g2[(long)orow[r] * 64 + ct * 16 + n] = f2h(acc[ct][r] * sc[r]);
    } else {
        const float* hf = (const float*)h1;
        for (long idx = (long)blockIdx.x * 256 + threadIdx.x; idx < (long)NODES * 64; idx += 782L * 256) {
            int row = (int)(idx >> 6), col = (int)(idx & 63);
            float acc = 0.f;
            for (int k = 0; k < 128; ++k) acc += hf[(long)row * 128 + k] * W2f[k * 64 + col];
            g2[idx] = f2h(acc * dinv[row]);
        }
    }
}

// ============ K7: gather layer 2 (half-wave/dest, fp16 128 B rows) -> h2 fp16 ========
__global__ __launch_bounds__(256) void gather2_kernel(
    const unsigned int* __restrict__ g2, const int* __restrict__ row_start,
    const int* __restrict__ counts, const int* __restrict__ esrc,
    const float* __restrict__ dinv, const float* __restrict__ bias,
    unsigned int* __restrict__ h2)
{
    int d = blockIdx.x * 8 + (threadIdx.x >> 5);
    int l = threadIdx.x & 31;
    int start = row_start[d], cnt = counts[d];
    float2 acc = make_float2(0.f, 0.f);
    int j = 0;
    for (; j + 4 <= cnt; j += 4) {
        int s0 = esrc[start + j + 0], s1 = esrc[start + j + 1];
        int s2 = esrc[start + j + 2], s3 = esrc[start + j + 3];
        float2 f0 = u2f2(g2[(long)s0 * 32 + l]);
        float2 f1 = u2f2(g2[(long)s1 * 32 + l]);
        float2 f2 = u2f2(g2[(long)s2 * 32 + l]);
        float2 f3 = u2f2(g2[(long)s3 * 32 + l]);
        acc.x += (f0.x + f1.x) + (f2.x + f3.x);
        acc.y += (f0.y + f1.y) + (f2.y + f3.y);
    }
    for (; j < cnt; ++j) {
        float2 f = u2f2(g2[(long)esrc[start + j] * 32 + l]);
        acc.x += f.x; acc.y += f.y;
    }
    float2 gd = u2f2(g2[(long)d * 32 + l]);
    float di = dinv[d];
    float2 b = *(const float2*)&bias[2 * l];
    h2[(long)d * 32 + l] = f22u(di * (acc.x + gd.x) + b.x, di * (acc.y + gd.y) + b.y);
}

// ============ K8: scoring ============
__global__ void score_kernel(const int* __restrict__ pos, const int* __restrict__ neg,
                             const unsigned int* __restrict__ h2, void* __restrict__ out,
                             const int* __restrict__ flag)
{
    int e = blockIdx.x * blockDim.x + threadIdx.x;
    if (e >= 2 * E_SCORE) return;
    int s, d;
    if (e < E_SCORE) { s = pos[e];           d = pos[E_SCORE + e]; }
    else             { int i = e - E_SCORE; s = neg[i]; d = neg[E_SCORE + i]; }
    const uint4* A = (const uint4*)(h2 + (long)s * 32);
    const uint4* B = (const uint4*)(h2 + (long)d * 32);
    float acc = 0.f;
    #pragma unroll
    for (int q = 0; q < 8; ++q) {
        uint4 ua = A[q], ub = B[q];
        float2 a0 = u2f2(ua.x), b0 = u2f2(ub.x);
        float2 a1 = u2f2(ua.y), b1 = u2f2(ub.y);
        float2 a2 = u2f2(ua.z), b2 = u2f2(ub.z);
        float2 a3 = u2f2(ua.w), b3 = u2f2(ub.w);
        acc += a0.x * b0.x + a0.y * b0.y + a1.x * b1.x + a1.y * b1.y
             + a2.x * b2.x + a2.y * b2.y + a3.x * b3.x + a3.y * b3.y;
    }
    if (flag[0]) ((unsigned short*)out)[e] = f2bf(acc);
    else         ((float*)out)[e] = acc;
}

extern "C" void kernel_launch(void* const* d_in, const int* in_sizes, int n_in,
                              void* d_out, int out_size, void* d_ws, size_t ws_size,
                              hipStream_t stream) {
    const void* x      = d_in[0];
    const int*  etrain = (const int*)d_in[1];
    const int*  pos    = (const int*)d_in[2];
    const int*  neg    = (const int*)d_in[3];
    const void* W1     = d_in[4];
    const void* b1     = d_in[5];
    const void* W2     = d_in[6];
    const void* b2     = d_in[7];

    char* base = (char*)d_ws;
    int*          flag      = (int*)(base + 0);
    int*          counts    = (int*)(base + 256);          // 200,000
    float*        dinv      = (float*)(base + 200256);     // 200,000
    int*          row_start = (int*)(base + 400256);       // 200,000
    int*          cursor    = (int*)(base + 600256);       // 200,000
    ushort_t*     W1T       = (ushort_t*)(base + 800256);  // 32,768  [n][k] bf16
    ushort_t*     W2T       = (ushort_t*)(base + 833024);  // 16,384  [n][k] bf16 (row len 128)
    float*        W1f       = (float*)(base + 849408);     // 65,536
    float*        W2f       = (float*)(base + 914944);     // 32,768
    float*        b1f       = (float*)(base + 947712);     //    512
    float*        b2f       = (float*)(base + 948224);     //    256
    int*          esrc      = (int*)(base + 948480);       // 2,400,000
    ushort_t*     g1        = (ushort_t*)(base + 3348480); // fp16 [N][128] 12.8 MB
    void*         h1        = (void*)(base + 16148480);    // bf16 12.8 MB (or fp32 25.6 MB)
    ushort_t*     g2        = g1;                          // reuse after gather1
    unsigned int* h2        = (unsigned int*)(base + 41748480); // fp16 [N][64] 6.4 MB

    const int* trow = etrain;
    const int* tcol = etrain + E_TRAIN;

    hipMemsetAsync(counts, 0, NODES * sizeof(int), stream);

    deg_detect_kernel<<<512, 256, 0, stream>>>(tcol, counts, (const unsigned int*)x, flag, E_TRAIN);

    scan_convert_kernel<<<5, 1024, 0, stream>>>(counts, row_start, cursor, dinv,
                                                W1, b1, W2, b2,
                                                W1T, W1f, W2T, W2f, b1f, b2f, flag);

    fill_gemm1_kernel<<<FILLB + 782, 256, 0, stream>>>(trow, tcol, cursor, esrc,
                                                       x, W1T, W1f, dinv, g1, flag);

    gather1_kernel<<<12500, 256, 0, stream>>>((const unsigned int*)g1, row_start, counts,
                                              esrc, dinv, b1f, h1, flag);

    gemm2_kernel<<<782, 256, 0, stream>>>(h1, W2T, W2f, dinv, g2, flag);

    gather2_kernel<<<6250, 256, 0, stream>>>((const unsigned int*)g2, row_start, counts,
                                             esrc, dinv, b2f, h2);

    score_kernel<<<1563, 256, 0, stream>>>(pos, neg, h2, d_out, flag);
}